// Round 4
// baseline (369.321 us; speedup 1.0000x reference)
//
#include <hip/hip_runtime.h>
#include <math.h>

constexpr int N_ = 1024;
constexpr int H_ = 128;
constexpr int D_ = 256;
constexpr int L_ = 3;
constexpr float EPS_ = 1e-5f;
constexpr float LOG2E_ = 1.44269504f;
constexpr int KLUT_ = 4096;
constexpr float DMAX_ = 40.0f;
constexpr float TSCALE_ = (KLUT_ - 1) / DMAX_;     // d -> table coordinate
constexpr float TMAX_ = (float)(KLUT_ - 1) - 0.001f;

__device__ __forceinline__ float fsig(float v) {            // sigmoid(v), ~1ulp
    float e = __builtin_amdgcn_exp2f(v * -LOG2E_);
    return __builtin_amdgcn_rcpf(1.0f + e);
}

// butterfly-equivalent reduction over each 16-lane row via DPP row_ror
template <int CTRL>
__device__ __forceinline__ float rowadd(float x) {
    int y = __builtin_amdgcn_update_dpp(0, __float_as_int(x), CTRL, 0xF, 0xF, true);
    return x + __int_as_float(y);
}
__device__ __forceinline__ float rowreduce16(float x) {
    x = rowadd<0x128>(x);   // row_ror:8
    x = rowadd<0x124>(x);   // row_ror:4
    x = rowadd<0x122>(x);   // row_ror:2
    x = rowadd<0x121>(x);   // row_ror:1
    return x;
}

#define LD8(dst, src)                                                     \
    {                                                                     \
        float4 t0_ = *(const float4*)(src);                               \
        float4 t1_ = *(const float4*)((src) + 4);                         \
        dst[0] = t0_.x; dst[1] = t0_.y; dst[2] = t0_.z; dst[3] = t0_.w;   \
        dst[4] = t1_.x; dst[5] = t1_.y; dst[6] = t1_.z; dst[7] = t1_.w;   \
    }

// ---------------- build ew LUT: lut[e][c] = LN(silu(scales(d_e)@deW+deb))*deg+debe ----
__global__ void k_lut(const float* __restrict__ deW, const float* __restrict__ deb,
                      const float* __restrict__ deg, const float* __restrict__ debe,
                      float* __restrict__ lut) {
    int e = blockIdx.x * 4 + (threadIdx.x >> 6);
    int lane = threadIdx.x & 63;
    float d = e * (DMAX_ / (KLUT_ - 1));
    float s0 = expf(-d), s1 = expf(-0.5f * d), s2 = expf(-0.25f * d);
    float v[2];
    float sum = 0.f, ssq = 0.f;
#pragma unroll
    for (int kk = 0; kk < 2; ++kk) {
        int c = lane + 64 * kk;
        float a = s0 * deW[c] + s1 * deW[H_ + c] + s2 * deW[2 * H_ + c] + deb[c];
        float sg = 1.f / (1.f + expf(-a));
        v[kk] = a * sg;
        sum += v[kk]; ssq += v[kk] * v[kk];
    }
#pragma unroll
    for (int mask = 1; mask < 64; mask <<= 1) {
        sum += __shfl_xor(sum, mask);
        ssq += __shfl_xor(ssq, mask);
    }
    float mu = sum * (1.f / H_);
    float var = ssq * (1.f / H_) - mu * mu;
    float rstd = 1.f / sqrtf(var + EPS_);
#pragma unroll
    for (int kk = 0; kk < 2; ++kk) {
        int c = lane + 64 * kk;
        lut[e * H_ + c] = (v[kk] - mu) * rstd * deg[c] + debe[c];
    }
}

// ---------------- x = emb[an]; pre = x@Wi + msg_b; prj = x@Wj ----------------
__global__ void k_embed_gemm(const int* __restrict__ an, const float* __restrict__ emb,
                             const float* __restrict__ W, const float* __restrict__ b,
                             float* __restrict__ x, float* __restrict__ preb,
                             float* __restrict__ prj) {
    int i = blockIdx.x;
    int t = threadIdx.x;               // 256 threads
    __shared__ float xr[H_];
    if (t < H_) {
        float xv = emb[an[i] * H_ + t];
        xr[t] = xv;
        x[i * H_ + t] = xv;
    }
    __syncthreads();
    int h = t & (H_ - 1);
    int off = (t >= H_) ? H_ : 0;
    float s = 0.f;
#pragma unroll 4
    for (int k = 0; k < H_; k += 4) {
        float4 xv = *(const float4*)&xr[k];
        s = fmaf(xv.x, W[(off + k) * H_ + h], s);
        s = fmaf(xv.y, W[(off + k + 1) * H_ + h], s);
        s = fmaf(xv.z, W[(off + k + 2) * H_ + h], s);
        s = fmaf(xv.w, W[(off + k + 3) * H_ + h], s);
    }
    if (t >= H_) prj[i * H_ + h] = s;
    else         preb[i * H_ + h] = s + b[h];
}

// ---------------- the big pairwise kernel (ew via LUT lerp) ----------------
// block = row i, 512 threads = 8 waves; each 16-lane row owns one pair (i,j);
// lane q (0..15 in row) owns 8 contiguous channels [8q, 8q+8).
__global__ __launch_bounds__(512, 8) void k_pair(
    const float* __restrict__ pos, const float* __restrict__ preb,
    const float* __restrict__ prj, const float* __restrict__ lut,
    const float* __restrict__ mgp, const float* __restrict__ mbep,
    float* __restrict__ msum) {
    const int i = blockIdx.x;
    const int tid = threadIdx.x;
    const int w = tid >> 6;            // 0..7
    const int lane = tid & 63;
    const int g = lane >> 4;
    const int q = lane & 15;
    const int p = w * 4 + g;           // 0..31: pair slot within block
    const int cb = q * 8;              // channel base

    __shared__ float dloc[N_];         // table coordinate per j

    float pbv[8], mgv[8], mbev[8], acc[8];
    LD8(pbv, preb + i * H_ + cb);
    LD8(mgv, mgp + cb);
    LD8(mbev, mbep + cb);
#pragma unroll
    for (int k = 0; k < 8; ++k) acc[k] = 0.f;

    const float pix = pos[3 * i], piy = pos[3 * i + 1], piz = pos[3 * i + 2];
    for (int j = tid; j < N_; j += 512) {
        float dx = pix - pos[3 * j];
        float dy = piy - pos[3 * j + 1];
        float dz = piz - pos[3 * j + 2];
        float sq = fmaf(dx, dx, fmaf(dy, dy, dz * dz));
        float d = __builtin_amdgcn_sqrtf(sq);
        dloc[j] = fminf(d * TSCALE_, TMAX_);
    }
    __syncthreads();

    for (int jt = 0; jt < N_; jt += 32) {
        const int j = jt + p;
        float tf = dloc[j];            // broadcast within 16-lane row
        int i0 = (int)tf;
        float fr = tf - (float)i0;
        const float* lp = lut + i0 * H_ + cb;
        float lo[8], hi[8], tm[8];
        LD8(lo, lp);
        LD8(hi, lp + H_);
        LD8(tm, prj + j * H_ + cb);

        float sum = 0.f, ssq = 0.f;
#pragma unroll
        for (int k = 0; k < 8; ++k) {
            float v = pbv[k] + tm[k];
            v *= fsig(v);
            tm[k] = v; sum += v; ssq = fmaf(v, v, ssq);
        }
        sum = rowreduce16(sum);
        ssq = rowreduce16(ssq);
        float mu = sum * (1.f / H_);
        float var = fmaf(ssq, 1.f / H_, -mu * mu);
        float rstd = __builtin_amdgcn_rsqf(var + EPS_);
        float c1 = -mu * rstd;
#pragma unroll
        for (int k = 0; k < 8; ++k) {
            float ew = fmaf(fr, hi[k] - lo[k], lo[k]);
            acc[k] = fmaf(fmaf(fmaf(tm[k], rstd, c1), mgv[k], mbev[k]), ew, acc[k]);
        }
    }

    // ---- combine the 32 pair-slots' partial sums ----
    __shared__ float red[32][H_];
    *(float4*)&red[p][cb] = make_float4(acc[0], acc[1], acc[2], acc[3]);
    *(float4*)&red[p][cb + 4] = make_float4(acc[4], acc[5], acc[6], acc[7]);
    __syncthreads();
    if (tid < H_) {
        float s = 0.f;
#pragma unroll
        for (int pp = 0; pp < 32; ++pp) s += red[pp][tid];
        msum[i * H_ + tid] = s;
    }
}

// ---- x += LN(silu([x,msum]@uW+ub)); lmean += x; then pre/prj for next level ----
__global__ void k_upd_gemm(const float* __restrict__ x_in, const float* __restrict__ msum,
                           const float* __restrict__ uW, const float* __restrict__ ub,
                           const float* __restrict__ ug, const float* __restrict__ ube,
                           const float* __restrict__ Wn, const float* __restrict__ bn,
                           float* __restrict__ x_out, float* __restrict__ lmean,
                           float* __restrict__ preb, float* __restrict__ prj) {
    int i = blockIdx.x;
    int t = threadIdx.x;               // 256 threads
    int h = t & (H_ - 1);
    int half = t >> 7;
    __shared__ float u[2 * H_];
    __shared__ float part[2][H_];
    __shared__ float xs[H_];
    __shared__ float r4[4][2];
    if (t < H_) u[t] = x_in[i * H_ + t];
    else        u[t] = msum[i * H_ + h];
    __syncthreads();
    float s = 0.f;
    const int kb = half * H_;
#pragma unroll 4
    for (int k = 0; k < H_; k += 4) {
        float4 uv = *(const float4*)&u[kb + k];
        s = fmaf(uv.x, uW[(kb + k) * H_ + h], s);
        s = fmaf(uv.y, uW[(kb + k + 1) * H_ + h], s);
        s = fmaf(uv.z, uW[(kb + k + 2) * H_ + h], s);
        s = fmaf(uv.w, uW[(kb + k + 3) * H_ + h], s);
    }
    part[half][h] = s;
    __syncthreads();
    float v = 0.f;
    if (t < H_) {
        float sv = part[0][t] + part[1][t] + ub[t];
        v = sv * fsig(sv);
    }
    float sum = v, ssq = v * v;
#pragma unroll
    for (int mask = 1; mask < 64; mask <<= 1) {
        sum += __shfl_xor(sum, mask);
        ssq += __shfl_xor(ssq, mask);
    }
    if ((t & 63) == 0) { r4[t >> 6][0] = sum; r4[t >> 6][1] = ssq; }
    __syncthreads();
    if (t < H_) {
        sum = r4[0][0] + r4[1][0];
        ssq = r4[0][1] + r4[1][1];
        float mu = sum * (1.f / H_);
        float var = fmaf(ssq, 1.f / H_, -mu * mu);
        float rstd = rsqrtf(var + EPS_);
        float xn = u[t] + fmaf((v - mu) * rstd, ug[t], ube[t]);
        xs[t] = xn;
        x_out[i * H_ + t] = xn;
        atomicAdd(&lmean[t], xn);
    }
    if (Wn) {
        __syncthreads();
        int off = (t >= H_) ? H_ : 0;
        float s2 = 0.f;
#pragma unroll 4
        for (int k = 0; k < H_; k += 4) {
            float4 xv = *(const float4*)&xs[k];
            s2 = fmaf(xv.x, Wn[(off + k) * H_ + h], s2);
            s2 = fmaf(xv.y, Wn[(off + k + 1) * H_ + h], s2);
            s2 = fmaf(xv.z, Wn[(off + k + 2) * H_ + h], s2);
            s2 = fmaf(xv.w, Wn[(off + k + 3) * H_ + h], s2);
        }
        if (t >= H_) prj[i * H_ + h] = s2;
        else         preb[i * H_ + h] = s2 + bn[h];
    }
}

// ---------------- out = LN(combined @ fp_W + fp_b) ----------------
__global__ void k_final(const float* __restrict__ lmean, const float* __restrict__ fpW,
                        const float* __restrict__ fpb, const float* __restrict__ fpg,
                        const float* __restrict__ fpbe, float* __restrict__ out) {
    int t = threadIdx.x;               // 256 threads
    __shared__ float comb[L_ * H_];    // 384
    comb[t] = lmean[t] * (1.f / N_);
    if (t < L_ * H_ - D_) comb[D_ + t] = lmean[D_ + t] * (1.f / N_);
    __syncthreads();
    float s = fpb[t];
#pragma unroll 8
    for (int k = 0; k < L_ * H_; ++k)
        s = fmaf(comb[k], fpW[k * D_ + t], s);
    float sum = s, ssq = s * s;
#pragma unroll
    for (int mask = 1; mask < 64; mask <<= 1) {
        sum += __shfl_xor(sum, mask);
        ssq += __shfl_xor(ssq, mask);
    }
    __shared__ float r4[4][2];
    int wv = t >> 6;
    if ((t & 63) == 0) { r4[wv][0] = sum; r4[wv][1] = ssq; }
    __syncthreads();
    sum = r4[0][0] + r4[1][0] + r4[2][0] + r4[3][0];
    ssq = r4[0][1] + r4[1][1] + r4[2][1] + r4[3][1];
    float mu = sum * (1.f / D_);
    float var = fmaf(ssq, 1.f / D_, -mu * mu);
    float rstd = rsqrtf(var + EPS_);
    out[t] = fmaf((s - mu) * rstd, fpg[t], fpbe[t]);
}

extern "C" void kernel_launch(void* const* d_in, const int* in_sizes, int n_in,
                              void* d_out, int out_size, void* d_ws, size_t ws_size,
                              hipStream_t stream) {
    const int*   an    = (const int*)d_in[0];
    const float* pos   = (const float*)d_in[1];
    const float* emb   = (const float*)d_in[2];
    const float* deW   = (const float*)d_in[3];
    const float* deb   = (const float*)d_in[4];
    const float* deg   = (const float*)d_in[5];
    const float* debe  = (const float*)d_in[6];
    const float* msgW  = (const float*)d_in[7];
    const float* msgb  = (const float*)d_in[8];
    const float* msgg  = (const float*)d_in[9];
    const float* msgbe = (const float*)d_in[10];
    const float* updW  = (const float*)d_in[11];
    const float* updb  = (const float*)d_in[12];
    const float* updg  = (const float*)d_in[13];
    const float* updbe = (const float*)d_in[14];
    const float* fpW   = (const float*)d_in[15];
    const float* fpb   = (const float*)d_in[16];
    const float* fpg   = (const float*)d_in[17];
    const float* fpbe  = (const float*)d_in[18];
    float* out = (float*)d_out;

    float* ws    = (float*)d_ws;
    float* x     = ws;                 // N*H
    float* preb  = x    + N_ * H_;     // N*H
    float* prj   = preb + N_ * H_;     // N*H
    float* msum  = prj  + N_ * H_;     // N*H
    float* lmean = msum + N_ * H_;     // L*H
    float* lut   = lmean + L_ * H_;    // KLUT*H (2 MB)

    hipMemsetAsync(lmean, 0, L_ * H_ * sizeof(float), stream);
    k_lut<<<KLUT_ / 4, 256, 0, stream>>>(deW, deb, deg, debe, lut);
    k_embed_gemm<<<N_, 256, 0, stream>>>(an, emb, msgW, msgb, x, preb, prj);
    for (int lvl = 0; lvl < L_; ++lvl) {
        k_pair<<<N_, 512, 0, stream>>>(pos, preb, prj, lut,
                                       msgg + lvl * H_, msgbe + lvl * H_, msum);
        const float* Wn = (lvl < L_ - 1) ? msgW + (lvl + 1) * 2 * H_ * H_ : nullptr;
        const float* bn = (lvl < L_ - 1) ? msgb + (lvl + 1) * H_ : nullptr;
        k_upd_gemm<<<N_, 256, 0, stream>>>(x, msum, updW + lvl * 2 * H_ * H_,
                                           updb + lvl * H_, updg + lvl * H_,
                                           updbe + lvl * H_, Wn, bn, x,
                                           lmean + lvl * H_, preb, prj);
    }
    k_final<<<1, D_, 0, stream>>>(lmean, fpW, fpb, fpg, fpbe, out);
}

// Round 5
// 243.764 us; speedup vs baseline: 1.5151x; 1.5151x over previous
//
#include <hip/hip_runtime.h>
#include <math.h>

constexpr int N_ = 1024;
constexpr int H_ = 128;
constexpr int D_ = 256;
constexpr int L_ = 3;
constexpr float EPS_ = 1e-5f;
constexpr float LOG2E_ = 1.44269504f;
constexpr int KLUT_ = 4096;
constexpr float DMAX_ = 40.0f;
constexpr float TSCALE_ = (KLUT_ - 1) / DMAX_;
constexpr float TMAX_ = (float)(KLUT_ - 1) - 0.001f;

__device__ __forceinline__ float fsig(float v) {            // sigmoid(v)
    float e = __builtin_amdgcn_exp2f(v * -LOG2E_);
    return __builtin_amdgcn_rcpf(1.0f + e);
}

template <int CTRL>
__device__ __forceinline__ float rowadd(float x) {
    int y = __builtin_amdgcn_update_dpp(0, __float_as_int(x), CTRL, 0xF, 0xF, true);
    return x + __int_as_float(y);
}
__device__ __forceinline__ float rowreduce16(float x) {
    x = rowadd<0x128>(x);   // row_ror:8
    x = rowadd<0x124>(x);   // row_ror:4
    x = rowadd<0x122>(x);   // row_ror:2
    x = rowadd<0x121>(x);   // row_ror:1
    return x;
}

__device__ __forceinline__ unsigned bfr(float x) {          // f32 -> bf16 bits (RNE)
    unsigned u = __float_as_uint(x);
    return (u + 0x7FFFu + ((u >> 16) & 1u)) >> 16;
}

#define LD8(dst, src)                                                     \
    {                                                                     \
        float4 t0_ = *(const float4*)(src);                               \
        float4 t1_ = *(const float4*)((src) + 4);                         \
        dst[0] = t0_.x; dst[1] = t0_.y; dst[2] = t0_.z; dst[3] = t0_.w;   \
        dst[4] = t1_.x; dst[5] = t1_.y; dst[6] = t1_.z; dst[7] = t1_.w;   \
    }

// ---- build packed ew LUT: word = bf16(f(e)) | bf16(f(e+1)-f(e))<<16 ----
__global__ void k_lut(const float* __restrict__ deW, const float* __restrict__ deb,
                      const float* __restrict__ deg, const float* __restrict__ debe,
                      unsigned* __restrict__ lutp) {
    int e = blockIdx.x * 4 + (threadIdx.x >> 6);
    int lane = threadIdx.x & 63;
    float res[2][2];
#pragma unroll
    for (int t = 0; t < 2; ++t) {
        int ee = min(e + t, KLUT_ - 1);
        float d = ee * (DMAX_ / (KLUT_ - 1));
        float s0 = expf(-d), s1 = expf(-0.5f * d), s2 = expf(-0.25f * d);
        float v[2];
        float sum = 0.f, ssq = 0.f;
#pragma unroll
        for (int kk = 0; kk < 2; ++kk) {
            int c = lane + 64 * kk;
            float a = s0 * deW[c] + s1 * deW[H_ + c] + s2 * deW[2 * H_ + c] + deb[c];
            float sg = 1.f / (1.f + expf(-a));
            v[kk] = a * sg;
            sum += v[kk]; ssq += v[kk] * v[kk];
        }
#pragma unroll
        for (int mask = 1; mask < 64; mask <<= 1) {
            sum += __shfl_xor(sum, mask);
            ssq += __shfl_xor(ssq, mask);
        }
        float mu = sum * (1.f / H_);
        float var = ssq * (1.f / H_) - mu * mu;
        float rstd = 1.f / sqrtf(var + EPS_);
#pragma unroll
        for (int kk = 0; kk < 2; ++kk) {
            int c = lane + 64 * kk;
            res[t][kk] = (v[kk] - mu) * rstd * deg[c] + debe[c];
        }
    }
#pragma unroll
    for (int kk = 0; kk < 2; ++kk) {
        int c = lane + 64 * kk;
        lutp[e * H_ + c] = bfr(res[0][kk]) | (bfr(res[1][kk] - res[0][kk]) << 16);
    }
}

// ---------------- x = emb[an]; pre = x@Wi + msg_b; prj = x@Wj ----------------
__global__ void k_embed_gemm(const int* __restrict__ an, const float* __restrict__ emb,
                             const float* __restrict__ W, const float* __restrict__ b,
                             float* __restrict__ x, float* __restrict__ preb,
                             float* __restrict__ prj) {
    int i = blockIdx.x;
    int t = threadIdx.x;               // 256 threads
    __shared__ float xr[H_];
    if (t < H_) {
        float xv = emb[an[i] * H_ + t];
        xr[t] = xv;
        x[i * H_ + t] = xv;
    }
    __syncthreads();
    int h = t & (H_ - 1);
    int off = (t >= H_) ? H_ : 0;
    float s = 0.f;
#pragma unroll 4
    for (int k = 0; k < H_; k += 4) {
        float4 xv = *(const float4*)&xr[k];
        s = fmaf(xv.x, W[(off + k) * H_ + h], s);
        s = fmaf(xv.y, W[(off + k + 1) * H_ + h], s);
        s = fmaf(xv.z, W[(off + k + 2) * H_ + h], s);
        s = fmaf(xv.w, W[(off + k + 3) * H_ + h], s);
    }
    if (t >= H_) prj[i * H_ + h] = s;
    else         preb[i * H_ + h] = s + b[h];
}

// ---- prefetch one j-tile's LUT word row + prj row + fr into registers ----
__device__ __forceinline__ void prf_step(int JT, int p, int cb, const int2* jinfo,
                                         const unsigned* __restrict__ lutp,
                                         const float* __restrict__ prjR,
                                         unsigned (&LW)[8], float (&TM)[8], float& FR) {
    int jw = (JT & (N_ - 1)) + p;
    int2 ji = jinfo[jw];
    FR = __int_as_float(ji.y);
    const unsigned* lp = (const unsigned*)((const char*)lutp + ji.x) + cb;
    uint4 a = *(const uint4*)lp;
    uint4 b = *(const uint4*)(lp + 4);
    LW[0] = a.x; LW[1] = a.y; LW[2] = a.z; LW[3] = a.w;
    LW[4] = b.x; LW[5] = b.y; LW[6] = b.z; LW[7] = b.w;
    LD8(TM, prjR + jw * H_ + cb);
}

// ---- compute one j-tile: silu+LN on message, lerp ew from packed LUT, accumulate ----
__device__ __forceinline__ void cmp_step(const unsigned (&LW)[8], float (&TM)[8], float FR,
                                         const float (&pbv)[8], const float (&mgv)[8],
                                         const float (&mbev)[8], float (&acc)[8]) {
    float sum = 0.f, ssq = 0.f;
#pragma unroll
    for (int k = 0; k < 8; ++k) {
        float v = pbv[k] + TM[k];
        v *= fsig(v);
        TM[k] = v; sum += v; ssq = fmaf(v, v, ssq);
    }
    sum = rowreduce16(sum);
    ssq = rowreduce16(ssq);
    float mu = sum * (1.f / H_);
    float var = fmaf(ssq, 1.f / H_, -mu * mu);
    float rstd = __builtin_amdgcn_rsqf(var + EPS_);
    float c1 = -mu * rstd;
#pragma unroll
    for (int k = 0; k < 8; ++k) {
        float lo = __uint_as_float(LW[k] << 16);
        float dl = __uint_as_float(LW[k] & 0xffff0000u);
        float ew = fmaf(FR, dl, lo);
        acc[k] = fmaf(fmaf(fmaf(TM[k], rstd, c1), mgv[k], mbev[k]), ew, acc[k]);
    }
}

// ---------------- pairwise kernel + fused update + next-level pre/prj ----------------
// block = row i, 512 threads = 8 waves; each 16-lane row owns one pair (i,j);
// lane q owns 8 contiguous channels [8q, 8q+8).
__global__ __launch_bounds__(512, 4) void k_pair(
    const float* __restrict__ pos, const float* __restrict__ x,
    const float* __restrict__ prebR, const float* __restrict__ prjR,
    const unsigned* __restrict__ lutp,
    const float* __restrict__ mgp, const float* __restrict__ mbep,
    const float* __restrict__ uW, const float* __restrict__ ub,
    const float* __restrict__ ug, const float* __restrict__ ube,
    const float* __restrict__ Wn, const float* __restrict__ bn,
    float* __restrict__ xout, float* __restrict__ lmean,
    float* __restrict__ prebW, float* __restrict__ prjW) {
    const int i = blockIdx.x;
    const int tid = threadIdx.x;
    const int w = tid >> 6;
    const int lane = tid & 63;
    const int g = lane >> 4;
    const int q = lane & 15;
    const int p = w * 4 + g;           // 0..31: pair slot
    const int cb = q * 8;              // channel base

    __shared__ int2 jinfo[N_];         // (lut row byte offset, fr bits)
    __shared__ float red[32][H_];
    __shared__ float msums[H_], xrow[H_], xs[H_];
    __shared__ float part[4][H_];
    __shared__ float r4[2][2];

    float pbv[8], mgv[8], mbev[8], acc[8];
    LD8(pbv, prebR + i * H_ + cb);
    LD8(mgv, mgp + cb);
    LD8(mbev, mbep + cb);
#pragma unroll
    for (int k = 0; k < 8; ++k) acc[k] = 0.f;

    const float pix = pos[3 * i], piy = pos[3 * i + 1], piz = pos[3 * i + 2];
    for (int j = tid; j < N_; j += 512) {
        float dx = pix - pos[3 * j];
        float dy = piy - pos[3 * j + 1];
        float dz = piz - pos[3 * j + 2];
        float sq = fmaf(dx, dx, fmaf(dy, dy, dz * dz));
        float d = __builtin_amdgcn_sqrtf(sq);
        float tf = fminf(d * TSCALE_, TMAX_);
        int i0 = (int)tf;
        jinfo[j] = make_int2(i0 * (H_ * 4), __float_as_int(tf - (float)i0));
    }
    if (tid < H_) xrow[tid] = x[i * H_ + tid];
    __syncthreads();

    // ---- software-pipelined j-loop (2 tiles in flight) ----
    unsigned lwA[8], lwB[8];
    float tmA[8], tmB[8], frA, frB;
    prf_step(0, p, cb, jinfo, lutp, prjR, lwA, tmA, frA);
    for (int jt = 0; jt < N_; jt += 64) {
        prf_step(jt + 32, p, cb, jinfo, lutp, prjR, lwB, tmB, frB);
        cmp_step(lwA, tmA, frA, pbv, mgv, mbev, acc);
        prf_step(jt + 64, p, cb, jinfo, lutp, prjR, lwA, tmA, frA);
        cmp_step(lwB, tmB, frB, pbv, mgv, mbev, acc);
    }

    // ---- combine 32 pair-slot partials -> msum (block-local) ----
    *(float4*)&red[p][cb] = make_float4(acc[0], acc[1], acc[2], acc[3]);
    *(float4*)&red[p][cb + 4] = make_float4(acc[4], acc[5], acc[6], acc[7]);
    __syncthreads();
    if (tid < H_) {
        float s = 0.f;
#pragma unroll
        for (int pp = 0; pp < 32; ++pp) s += red[pp][tid];
        msums[tid] = s;
    }
    __syncthreads();

    // ---- fused update: x += LN(silu([x,msum]@uW+ub)); lmean += x ----
    int h = tid & (H_ - 1);
    int seg = tid >> 7;                // 4-way K split
    const float* src = (seg == 0) ? xrow : (seg == 1) ? xrow + 64
                     : (seg == 2) ? msums : msums + 64;
    const float* Wp = uW + (seg * 64) * H_ + h;
    float s2 = 0.f;
#pragma unroll 4
    for (int k = 0; k < 64; k += 4) {
        float4 uv = *(const float4*)&src[k];
        s2 = fmaf(uv.x, Wp[(k + 0) * H_], s2);
        s2 = fmaf(uv.y, Wp[(k + 1) * H_], s2);
        s2 = fmaf(uv.z, Wp[(k + 2) * H_], s2);
        s2 = fmaf(uv.w, Wp[(k + 3) * H_], s2);
    }
    part[seg][h] = s2;
    __syncthreads();
    float v = 0.f;
    if (tid < H_) {
        float sv = part[0][tid] + part[1][tid] + part[2][tid] + part[3][tid] + ub[tid];
        v = sv * fsig(sv);
    }
    float sum = v, ssq = v * v;
#pragma unroll
    for (int mask = 1; mask < 64; mask <<= 1) {
        sum += __shfl_xor(sum, mask);
        ssq += __shfl_xor(ssq, mask);
    }
    if (tid < H_ && (tid & 63) == 0) { r4[tid >> 6][0] = sum; r4[tid >> 6][1] = ssq; }
    __syncthreads();
    if (tid < H_) {
        sum = r4[0][0] + r4[1][0];
        ssq = r4[0][1] + r4[1][1];
        float mu = sum * (1.f / H_);
        float var = fmaf(ssq, 1.f / H_, -mu * mu);
        float rstd = rsqrtf(var + EPS_);
        float xn = xrow[tid] + fmaf((v - mu) * rstd, ug[tid], ube[tid]);
        xs[tid] = xn;
        xout[i * H_ + tid] = xn;
        atomicAdd(&lmean[tid], xn);
    }

    // ---- fused next-level pre/prj = xs @ Wn (+bn), into ping-pong buffers ----
    if (Wn) {
        __syncthreads();               // xs ready; also all part reads done
        int which = tid >> 8;          // 0 = pre, 1 = prj
        int kh = (tid >> 7) & 1;       // K half
        const float* Wp2 = Wn + (which * H_ + kh * 64) * H_ + h;
        const float* xsrc = xs + kh * 64;
        float s3 = 0.f;
#pragma unroll 4
        for (int k = 0; k < 64; k += 4) {
            float4 xv = *(const float4*)&xsrc[k];
            s3 = fmaf(xv.x, Wp2[(k + 0) * H_], s3);
            s3 = fmaf(xv.y, Wp2[(k + 1) * H_], s3);
            s3 = fmaf(xv.z, Wp2[(k + 2) * H_], s3);
            s3 = fmaf(xv.w, Wp2[(k + 3) * H_], s3);
        }
        part[(which << 1) | kh][h] = s3;
        __syncthreads();
        if (tid < 256) {
            int wh = tid >> 7, h3 = tid & 127;
            float val = part[wh * 2][h3] + part[wh * 2 + 1][h3];
            if (wh) prjW[i * H_ + h3] = val;
            else    prebW[i * H_ + h3] = val + bn[h3];
        }
    }
}

// ---------------- out = LN(combined @ fp_W + fp_b) ----------------
__global__ void k_final(const float* __restrict__ lmean, const float* __restrict__ fpW,
                        const float* __restrict__ fpb, const float* __restrict__ fpg,
                        const float* __restrict__ fpbe, float* __restrict__ out) {
    int t = threadIdx.x;               // 256 threads
    __shared__ float comb[L_ * H_];
    comb[t] = lmean[t] * (1.f / N_);
    if (t < L_ * H_ - D_) comb[D_ + t] = lmean[D_ + t] * (1.f / N_);
    __syncthreads();
    float s = fpb[t];
#pragma unroll 8
    for (int k = 0; k < L_ * H_; ++k)
        s = fmaf(comb[k], fpW[k * D_ + t], s);
    float sum = s, ssq = s * s;
#pragma unroll
    for (int mask = 1; mask < 64; mask <<= 1) {
        sum += __shfl_xor(sum, mask);
        ssq += __shfl_xor(ssq, mask);
    }
    __shared__ float r4[4][2];
    int wv = t >> 6;
    if ((t & 63) == 0) { r4[wv][0] = sum; r4[wv][1] = ssq; }
    __syncthreads();
    sum = r4[0][0] + r4[1][0] + r4[2][0] + r4[3][0];
    ssq = r4[0][1] + r4[1][1] + r4[2][1] + r4[3][1];
    float mu = sum * (1.f / D_);
    float var = fmaf(ssq, 1.f / D_, -mu * mu);
    float rstd = rsqrtf(var + EPS_);
    out[t] = fmaf((s - mu) * rstd, fpg[t], fpbe[t]);
}

extern "C" void kernel_launch(void* const* d_in, const int* in_sizes, int n_in,
                              void* d_out, int out_size, void* d_ws, size_t ws_size,
                              hipStream_t stream) {
    const int*   an    = (const int*)d_in[0];
    const float* pos   = (const float*)d_in[1];
    const float* emb   = (const float*)d_in[2];
    const float* deW   = (const float*)d_in[3];
    const float* deb   = (const float*)d_in[4];
    const float* deg   = (const float*)d_in[5];
    const float* debe  = (const float*)d_in[6];
    const float* msgW  = (const float*)d_in[7];
    const float* msgb  = (const float*)d_in[8];
    const float* msgg  = (const float*)d_in[9];
    const float* msgbe = (const float*)d_in[10];
    const float* updW  = (const float*)d_in[11];
    const float* updb  = (const float*)d_in[12];
    const float* updg  = (const float*)d_in[13];
    const float* updbe = (const float*)d_in[14];
    const float* fpW   = (const float*)d_in[15];
    const float* fpb   = (const float*)d_in[16];
    const float* fpg   = (const float*)d_in[17];
    const float* fpbe  = (const float*)d_in[18];
    float* out = (float*)d_out;

    float* ws    = (float*)d_ws;
    float* x     = ws;                 // N*H
    float* prebA = x + N_ * H_;        // N*H
    float* prjA  = prebA + N_ * H_;    // N*H
    float* prebB = prjA + N_ * H_;     // N*H
    float* prjB  = prebB + N_ * H_;    // N*H
    float* lmean = prjB + N_ * H_;     // L*H
    unsigned* lutp = (unsigned*)(lmean + L_ * H_);   // KLUT*H words (2 MB)

    hipMemsetAsync(lmean, 0, L_ * H_ * sizeof(float), stream);
    k_lut<<<KLUT_ / 4, 256, 0, stream>>>(deW, deb, deg, debe, lutp);
    k_embed_gemm<<<N_, 256, 0, stream>>>(an, emb, msgW, msgb, x, prebA, prjA);
    for (int lvl = 0; lvl < L_; ++lvl) {
        const float* pR  = (lvl & 1) ? prebB : prebA;
        const float* prR = (lvl & 1) ? prjB  : prjA;
        float* pW  = (lvl & 1) ? prebA : prebB;
        float* prW = (lvl & 1) ? prjA  : prjB;
        const float* Wn = (lvl < L_ - 1) ? msgW + (lvl + 1) * 2 * H_ * H_ : nullptr;
        const float* bn = (lvl < L_ - 1) ? msgb + (lvl + 1) * H_ : nullptr;
        k_pair<<<N_, 512, 0, stream>>>(pos, x, pR, prR, lutp,
                                       msgg + lvl * H_, msgbe + lvl * H_,
                                       updW + lvl * 2 * H_ * H_, updb + lvl * H_,
                                       updg + lvl * H_, updbe + lvl * H_,
                                       Wn, bn, x, lmean + lvl * H_, pW, prW);
    }
    k_final<<<1, D_, 0, stream>>>(lmean, fpW, fpb, fpg, fpbe, out);
}

// Round 6
// 234.389 us; speedup vs baseline: 1.5757x; 1.0400x over previous
//
#include <hip/hip_runtime.h>
#include <math.h>

constexpr int N_ = 1024;
constexpr int H_ = 128;
constexpr int D_ = 256;
constexpr int L_ = 3;
constexpr float EPS_ = 1e-5f;
constexpr float LOG2E_ = 1.44269504f;
constexpr int KLUT_ = 8192;
constexpr float DMAX_ = 40.0f;
constexpr float TSCALE_ = (KLUT_ - 1) / DMAX_;
constexpr float TMAX_ = (float)(KLUT_ - 1) - 0.001f;

__device__ __forceinline__ float fsig(float v) {            // sigmoid(v)
    float e = __builtin_amdgcn_exp2f(v * -LOG2E_);
    return __builtin_amdgcn_rcpf(1.0f + e);
}

template <int CTRL>
__device__ __forceinline__ float rowadd(float x) {
    int y = __builtin_amdgcn_update_dpp(0, __float_as_int(x), CTRL, 0xF, 0xF, true);
    return x + __int_as_float(y);
}
__device__ __forceinline__ float rowreduce16(float x) {
    x = rowadd<0x128>(x);   // row_ror:8
    x = rowadd<0x124>(x);   // row_ror:4
    x = rowadd<0x122>(x);   // row_ror:2
    x = rowadd<0x121>(x);   // row_ror:1
    return x;
}

#define LD8(dst, src)                                                     \
    {                                                                     \
        float4 t0_ = *(const float4*)(src);                               \
        float4 t1_ = *(const float4*)((src) + 4);                         \
        dst[0] = t0_.x; dst[1] = t0_.y; dst[2] = t0_.z; dst[3] = t0_.w;   \
        dst[4] = t1_.x; dst[5] = t1_.y; dst[6] = t1_.z; dst[7] = t1_.w;   \
    }

// ---- build f32 ew LUT (nearest-neighbor): lut[e][c] = LN(silu(scales(d_e)@deW+deb))*g+be ----
__global__ void k_lut(const float* __restrict__ deW, const float* __restrict__ deb,
                      const float* __restrict__ deg, const float* __restrict__ debe,
                      float* __restrict__ lut) {
    int e = blockIdx.x * 4 + (threadIdx.x >> 6);
    int lane = threadIdx.x & 63;
    float d = e * (DMAX_ / (KLUT_ - 1));
    float s0 = expf(-d), s1 = expf(-0.5f * d), s2 = expf(-0.25f * d);
    float v[2];
    float sum = 0.f, ssq = 0.f;
#pragma unroll
    for (int kk = 0; kk < 2; ++kk) {
        int c = lane + 64 * kk;
        float a = s0 * deW[c] + s1 * deW[H_ + c] + s2 * deW[2 * H_ + c] + deb[c];
        float sg = 1.f / (1.f + expf(-a));
        v[kk] = a * sg;
        sum += v[kk]; ssq += v[kk] * v[kk];
    }
#pragma unroll
    for (int mask = 1; mask < 64; mask <<= 1) {
        sum += __shfl_xor(sum, mask);
        ssq += __shfl_xor(ssq, mask);
    }
    float mu = sum * (1.f / H_);
    float var = ssq * (1.f / H_) - mu * mu;
    float rstd = 1.f / sqrtf(var + EPS_);
#pragma unroll
    for (int kk = 0; kk < 2; ++kk) {
        int c = lane + 64 * kk;
        lut[e * H_ + c] = (v[kk] - mu) * rstd * deg[c] + debe[c];
    }
}

// ---------------- x = emb[an]; pre = x@Wi + msg_b; prj = x@Wj ----------------
__global__ void k_embed_gemm(const int* __restrict__ an, const float* __restrict__ emb,
                             const float* __restrict__ W, const float* __restrict__ b,
                             float* __restrict__ x, float* __restrict__ preb,
                             float* __restrict__ prj) {
    int i = blockIdx.x;
    int t = threadIdx.x;               // 256 threads
    __shared__ float xr[H_];
    if (t < H_) {
        float xv = emb[an[i] * H_ + t];
        xr[t] = xv;
        x[i * H_ + t] = xv;
    }
    __syncthreads();
    int h = t & (H_ - 1);
    int off = (t >= H_) ? H_ : 0;
    float s = 0.f;
#pragma unroll 4
    for (int k = 0; k < H_; k += 4) {
        float4 xv = *(const float4*)&xr[k];
        s = fmaf(xv.x, W[(off + k) * H_ + h], s);
        s = fmaf(xv.y, W[(off + k + 1) * H_ + h], s);
        s = fmaf(xv.z, W[(off + k + 2) * H_ + h], s);
        s = fmaf(xv.w, W[(off + k + 3) * H_ + h], s);
    }
    if (t >= H_) prj[i * H_ + h] = s;
    else         preb[i * H_ + h] = s + b[h];
}

// ---- prefetch one j-tile's LUT row + prj row into registers ----
__device__ __forceinline__ void prf_step(int JT, int p, int cb, const int* jinfo,
                                         const float* __restrict__ lut,
                                         const float* __restrict__ prjR,
                                         float (&EW)[8], float (&TM)[8]) {
    int jw = (JT & (N_ - 1)) + p;
    int jof = jinfo[jw];               // byte offset of NN lut row
    const float* lp = (const float*)((const char*)lut + jof) + cb;
    LD8(EW, lp);
    LD8(TM, prjR + jw * H_ + cb);
}

// ---- compute one j-tile: silu+LN stats on message; acc1 += t*ew, acc2 += ew ----
__device__ __forceinline__ void cmp_step(const float (&EW)[8], float (&TM)[8],
                                         const float (&pbv)[8],
                                         float (&acc1)[8], float (&acc2)[8]) {
    float sum = 0.f, ssq = 0.f;
#pragma unroll
    for (int k = 0; k < 8; ++k) {
        float w = pbv[k] + TM[k];
        float vv = w * fsig(w);
        TM[k] = vv; sum += vv; ssq = fmaf(vv, vv, ssq);
    }
    sum = rowreduce16(sum);
    ssq = rowreduce16(ssq);
    float mu = sum * (1.f / H_);
    float var = fmaf(ssq, 1.f / H_, -mu * mu);
    float rstd = __builtin_amdgcn_rsqf(var + EPS_);
    float c1 = -mu * rstd;
#pragma unroll
    for (int k = 0; k < 8; ++k) {
        float t = fmaf(TM[k], rstd, c1);          // (v-mu)*rstd
        acc1[k] = fmaf(t, EW[k], acc1[k]);        // Σ t*ew  (scaled by g later)
        acc2[k] += EW[k];                         // Σ ew    (scaled by be later)
    }
}

// ---------------- pairwise kernel + fused update + next-level pre/prj ----------------
// block = row i, 512 threads = 8 waves; each 16-lane row owns one pair (i,j);
// lane q owns 8 contiguous channels [8q, 8q+8).
__global__ __launch_bounds__(512, 4) void k_pair(
    const float* __restrict__ pos, const float* __restrict__ x,
    const float* __restrict__ prebR, const float* __restrict__ prjR,
    const float* __restrict__ lut,
    const float* __restrict__ mgp, const float* __restrict__ mbep,
    const float* __restrict__ uW, const float* __restrict__ ub,
    const float* __restrict__ ug, const float* __restrict__ ube,
    const float* __restrict__ Wn, const float* __restrict__ bn,
    float* __restrict__ xout, float* __restrict__ lmean,
    float* __restrict__ prebW, float* __restrict__ prjW) {
    const int i = blockIdx.x;
    const int tid = threadIdx.x;
    const int w = tid >> 6;
    const int lane = tid & 63;
    const int g = lane >> 4;
    const int q = lane & 15;
    const int p = w * 4 + g;           // 0..31: pair slot
    const int cb = q * 8;              // channel base

    __shared__ int jinfo[N_];          // NN lut row byte offset per j
    __shared__ float red[32][H_];
    __shared__ float msums[H_], xrow[H_], xs[H_];
    __shared__ float part[4][H_];
    __shared__ float r4[2][2];

    float pbv[8], acc1[8], acc2[8];
    LD8(pbv, prebR + i * H_ + cb);
#pragma unroll
    for (int k = 0; k < 8; ++k) { acc1[k] = 0.f; acc2[k] = 0.f; }

    const float pix = pos[3 * i], piy = pos[3 * i + 1], piz = pos[3 * i + 2];
    for (int j = tid; j < N_; j += 512) {
        float dx = pix - pos[3 * j];
        float dy = piy - pos[3 * j + 1];
        float dz = piz - pos[3 * j + 2];
        float sq = fmaf(dx, dx, fmaf(dy, dy, dz * dz));
        float d = __builtin_amdgcn_sqrtf(sq);
        float tf = fminf(d * TSCALE_, TMAX_);
        int i0 = (int)(tf + 0.5f);     // nearest entry
        jinfo[j] = i0 * (H_ * 4);
    }
    if (tid < H_) xrow[tid] = x[i * H_ + tid];
    __syncthreads();

    // ---- software-pipelined j-loop (2 tiles in flight, schedule pinned) ----
    float ewA[8], tmA[8], ewB[8], tmB[8];
    prf_step(0, p, cb, jinfo, lut, prjR, ewA, tmA);
    __builtin_amdgcn_sched_barrier(0);
    for (int jt = 0; jt < N_; jt += 64) {
        prf_step(jt + 32, p, cb, jinfo, lut, prjR, ewB, tmB);
        __builtin_amdgcn_sched_barrier(0);
        cmp_step(ewA, tmA, pbv, acc1, acc2);
        __builtin_amdgcn_sched_barrier(0);
        prf_step(jt + 64, p, cb, jinfo, lut, prjR, ewA, tmA);
        __builtin_amdgcn_sched_barrier(0);
        cmp_step(ewB, tmB, pbv, acc1, acc2);
        __builtin_amdgcn_sched_barrier(0);
    }

    // ---- apply g/be and combine 32 pair-slot partials -> msum (block-local) ----
    float mgv[8], mbev[8], acc[8];
    LD8(mgv, mgp + cb);
    LD8(mbev, mbep + cb);
#pragma unroll
    for (int k = 0; k < 8; ++k)
        acc[k] = mgv[k] * acc1[k] + mbev[k] * acc2[k];
    *(float4*)&red[p][cb] = make_float4(acc[0], acc[1], acc[2], acc[3]);
    *(float4*)&red[p][cb + 4] = make_float4(acc[4], acc[5], acc[6], acc[7]);
    __syncthreads();
    if (tid < H_) {
        float s = 0.f;
#pragma unroll
        for (int pp = 0; pp < 32; ++pp) s += red[pp][tid];
        msums[tid] = s;
    }
    __syncthreads();

    // ---- fused update: x += LN(silu([x,msum]@uW+ub)); lmean += x ----
    int h = tid & (H_ - 1);
    int seg = tid >> 7;                // 4-way K split
    const float* src = (seg == 0) ? xrow : (seg == 1) ? xrow + 64
                     : (seg == 2) ? msums : msums + 64;
    const float* Wp = uW + (seg * 64) * H_ + h;
    float s2 = 0.f;
#pragma unroll 4
    for (int k = 0; k < 64; k += 4) {
        float4 uv = *(const float4*)&src[k];
        s2 = fmaf(uv.x, Wp[(k + 0) * H_], s2);
        s2 = fmaf(uv.y, Wp[(k + 1) * H_], s2);
        s2 = fmaf(uv.z, Wp[(k + 2) * H_], s2);
        s2 = fmaf(uv.w, Wp[(k + 3) * H_], s2);
    }
    part[seg][h] = s2;
    __syncthreads();
    float v = 0.f;
    if (tid < H_) {
        float sv = part[0][tid] + part[1][tid] + part[2][tid] + part[3][tid] + ub[tid];
        v = sv * fsig(sv);
    }
    float sum = v, ssq = v * v;
#pragma unroll
    for (int mask = 1; mask < 64; mask <<= 1) {
        sum += __shfl_xor(sum, mask);
        ssq += __shfl_xor(ssq, mask);
    }
    if (tid < H_ && (tid & 63) == 0) { r4[tid >> 6][0] = sum; r4[tid >> 6][1] = ssq; }
    __syncthreads();
    if (tid < H_) {
        sum = r4[0][0] + r4[1][0];
        ssq = r4[0][1] + r4[1][1];
        float mu = sum * (1.f / H_);
        float var = fmaf(ssq, 1.f / H_, -mu * mu);
        float rstd = rsqrtf(var + EPS_);
        float xn = xrow[tid] + fmaf((v - mu) * rstd, ug[tid], ube[tid]);
        xs[tid] = xn;
        xout[i * H_ + tid] = xn;
        atomicAdd(&lmean[tid], xn);
    }

    // ---- fused next-level pre/prj = xs @ Wn (+bn), into ping-pong buffers ----
    if (Wn) {
        __syncthreads();               // xs ready; also all part reads done
        int which = tid >> 8;          // 0 = pre, 1 = prj
        int kh = (tid >> 7) & 1;       // K half
        const float* Wp2 = Wn + (which * H_ + kh * 64) * H_ + h;
        const float* xsrc = xs + kh * 64;
        float s3 = 0.f;
#pragma unroll 4
        for (int k = 0; k < 64; k += 4) {
            float4 xv = *(const float4*)&xsrc[k];
            s3 = fmaf(xv.x, Wp2[(k + 0) * H_], s3);
            s3 = fmaf(xv.y, Wp2[(k + 1) * H_], s3);
            s3 = fmaf(xv.z, Wp2[(k + 2) * H_], s3);
            s3 = fmaf(xv.w, Wp2[(k + 3) * H_], s3);
        }
        part[(which << 1) | kh][h] = s3;
        __syncthreads();
        if (tid < 256) {
            int wh = tid >> 7, h3 = tid & 127;
            float val = part[wh * 2][h3] + part[wh * 2 + 1][h3];
            if (wh) prjW[i * H_ + h3] = val;
            else    prebW[i * H_ + h3] = val + bn[h3];
        }
    }
}

// ---------------- out = LN(combined @ fp_W + fp_b) ----------------
__global__ void k_final(const float* __restrict__ lmean, const float* __restrict__ fpW,
                        const float* __restrict__ fpb, const float* __restrict__ fpg,
                        const float* __restrict__ fpbe, float* __restrict__ out) {
    int t = threadIdx.x;               // 256 threads
    __shared__ float comb[L_ * H_];
    comb[t] = lmean[t] * (1.f / N_);
    if (t < L_ * H_ - D_) comb[D_ + t] = lmean[D_ + t] * (1.f / N_);
    __syncthreads();
    float s = fpb[t];
#pragma unroll 8
    for (int k = 0; k < L_ * H_; ++k)
        s = fmaf(comb[k], fpW[k * D_ + t], s);
    float sum = s, ssq = s * s;
#pragma unroll
    for (int mask = 1; mask < 64; mask <<= 1) {
        sum += __shfl_xor(sum, mask);
        ssq += __shfl_xor(ssq, mask);
    }
    __shared__ float r4[4][2];
    int wv = t >> 6;
    if ((t & 63) == 0) { r4[wv][0] = sum; r4[wv][1] = ssq; }
    __syncthreads();
    sum = r4[0][0] + r4[1][0] + r4[2][0] + r4[3][0];
    ssq = r4[0][1] + r4[1][1] + r4[2][1] + r4[3][1];
    float mu = sum * (1.f / D_);
    float var = fmaf(ssq, 1.f / D_, -mu * mu);
    float rstd = rsqrtf(var + EPS_);
    out[t] = fmaf((s - mu) * rstd, fpg[t], fpbe[t]);
}

extern "C" void kernel_launch(void* const* d_in, const int* in_sizes, int n_in,
                              void* d_out, int out_size, void* d_ws, size_t ws_size,
                              hipStream_t stream) {
    const int*   an    = (const int*)d_in[0];
    const float* pos   = (const float*)d_in[1];
    const float* emb   = (const float*)d_in[2];
    const float* deW   = (const float*)d_in[3];
    const float* deb   = (const float*)d_in[4];
    const float* deg   = (const float*)d_in[5];
    const float* debe  = (const float*)d_in[6];
    const float* msgW  = (const float*)d_in[7];
    const float* msgb  = (const float*)d_in[8];
    const float* msgg  = (const float*)d_in[9];
    const float* msgbe = (const float*)d_in[10];
    const float* updW  = (const float*)d_in[11];
    const float* updb  = (const float*)d_in[12];
    const float* updg  = (const float*)d_in[13];
    const float* updbe = (const float*)d_in[14];
    const float* fpW   = (const float*)d_in[15];
    const float* fpb   = (const float*)d_in[16];
    const float* fpg   = (const float*)d_in[17];
    const float* fpbe  = (const float*)d_in[18];
    float* out = (float*)d_out;

    float* ws    = (float*)d_ws;
    float* x     = ws;                 // N*H
    float* prebA = x + N_ * H_;        // N*H
    float* prjA  = prebA + N_ * H_;    // N*H
    float* prebB = prjA + N_ * H_;     // N*H
    float* prjB  = prebB + N_ * H_;    // N*H
    float* lmean = prjB + N_ * H_;     // L*H
    float* lut   = lmean + L_ * H_;    // KLUT*H f32 (4 MB)

    hipMemsetAsync(lmean, 0, L_ * H_ * sizeof(float), stream);
    k_lut<<<KLUT_ / 4, 256, 0, stream>>>(deW, deb, deg, debe, lut);
    k_embed_gemm<<<N_, 256, 0, stream>>>(an, emb, msgW, msgb, x, prebA, prjA);
    for (int lvl = 0; lvl < L_; ++lvl) {
        const float* pR  = (lvl & 1) ? prebB : prebA;
        const float* prR = (lvl & 1) ? prjB  : prjA;
        float* pW  = (lvl & 1) ? prebA : prebB;
        float* prW = (lvl & 1) ? prjA  : prjB;
        const float* Wn = (lvl < L_ - 1) ? msgW + (lvl + 1) * 2 * H_ * H_ : nullptr;
        const float* bn = (lvl < L_ - 1) ? msgb + (lvl + 1) * H_ : nullptr;
        k_pair<<<N_, 512, 0, stream>>>(pos, x, pR, prR, lut,
                                       msgg + lvl * H_, msgbe + lvl * H_,
                                       updW + lvl * 2 * H_ * H_, updb + lvl * H_,
                                       updg + lvl * H_, updbe + lvl * H_,
                                       Wn, bn, x, lmean + lvl * H_, pW, prW);
    }
    k_final<<<1, D_, 0, stream>>>(lmean, fpW, fpb, fpg, fpbe, out);
}